// Round 7
// baseline (537.506 us; speedup 1.0000x reference)
//
#include <hip/hip_runtime.h>

#define FEPS 1e-5f

constexpr int Bn = 4, Hn = 16, Sn = 4096, Dn = 64;
constexpr int NHEAD = Bn * Hn;          // 64 heads
constexpr int SLOT = Dn * Dn + Dn;      // 4160 floats: kv then ksum

// ---------------- Pass 1: partial kv = K^T V and k_sum over an S-chunk ----------------
// Register-staged, wave-private pipeline (R6 main loop, unchanged):
//   per stage: global float4 -> regs (next stage) | compute current stage from
//   this wave's own LDS quarter | ds_write regs -> same quarter. No barriers
//   in the loop.
// R7 change: epilogue reduction now uses ONE 16KB buffer reduced serially by
// the 4 waves (was 2x16KB parallel) -> LDS 33KB -> 17KB, and
// __launch_bounds__(256,5) -> up to 5 blocks/CU (VGPR cap 102; R6 needed 80).
__global__ __launch_bounds__(256, 5) void pass1(const float* __restrict__ K,
                                                const float* __restrict__ V,
                                                float* __restrict__ part,
                                                int ch_s) {
    // [0..2047] staging {K 1024 | V 1024} during loop; [0..4095] red + [4096..4351] ksred in epilogue
    __shared__ float lds[4352];   // 17 KB

    const int head = blockIdx.x;
    const int chunk = blockIdx.y;
    const int t = threadIdx.x;
    const int w = t >> 6;                  // wave 0..3
    const int l = t & 63;
    const int d0 = (l >> 3) * 8;           // kv row-tile base (K dim)
    const int e0 = (l & 7) * 8;            // kv col-tile base (V dim)
    const int nstg = ch_s / 16;            // 16 rows per stage block-wide, 4 per wave

    const size_t base = ((size_t)head * Sn + (size_t)chunk * ch_s) * Dn;
    // wave w owns rows [w*4, w*4+4) of every 16-row stage
    const float* Kg = K + base + (size_t)w * 256 + l * 4;   // + st*1024 per stage
    const float* Vg = V + base + (size_t)w * 256 + l * 4;

    float* kq = &lds[w * 256];             // this wave's K quarter (4 rows x 64)
    float* vq = &lds[1024 + w * 256];      // this wave's V quarter

    float acc[8][8] = {};
    float ks[8] = {};

    // prologue: stage 0 into LDS
    {
        float4 kr = *(const float4*)Kg;
        float4 vr = *(const float4*)Vg;
        *(float4*)(kq + l * 4) = kr;
        *(float4*)(vq + l * 4) = vr;
    }

    for (int st = 0; st < nstg; ++st) {
        float4 kn, vn;
        const bool more = (st + 1 < nstg);
        if (more) {
            kn = *(const float4*)(Kg + (size_t)(st + 1) * 1024);
            vn = *(const float4*)(Vg + (size_t)(st + 1) * 1024);
        }
        // compute this wave's 4 rows of the current stage
        #pragma unroll
        for (int r = 0; r < 4; ++r) {
            float4 ka = *(const float4*)(kq + r * 64 + d0);
            float4 kc = *(const float4*)(kq + r * 64 + d0 + 4);
            float4 va = *(const float4*)(vq + r * 64 + e0);
            float4 vc = *(const float4*)(vq + r * 64 + e0 + 4);
            float kf[8] = {ka.x, ka.y, ka.z, ka.w, kc.x, kc.y, kc.z, kc.w};
            float vf[8] = {va.x, va.y, va.z, va.w, vc.x, vc.y, vc.z, vc.w};
            #pragma unroll
            for (int i = 0; i < 8; ++i) {
                ks[i] += kf[i];
                #pragma unroll
                for (int j = 0; j < 8; ++j) acc[i][j] += kf[i] * vf[j];
            }
        }
        // overwrite the just-consumed quarter with the next stage (in-order DS)
        if (more) {
            *(float4*)(kq + l * 4) = kn;
            *(float4*)(vq + l * 4) = vn;
        }
    }

    // ---- serial block reduction: one 16KB buffer, 4 phases ----
    __syncthreads();                       // all waves done with staging area
    float* red = &lds[0];                  // 4096 floats (overlaps staging)
    float* ksr = &lds[4096];               // 256 floats
    if ((l & 7) == 0) {                    // 8 lanes/wave hold ks for d0..d0+7
        #pragma unroll
        for (int i = 0; i < 8; ++i) ksr[w * Dn + d0 + i] = ks[i];
    }
    #pragma unroll
    for (int ww = 0; ww < 4; ++ww) {
        if (w == ww) {
            #pragma unroll
            for (int i = 0; i < 8; ++i) {
                float* p = &red[(d0 + i) * Dn + e0];
                if (ww == 0) {
                    *(float4*)p = make_float4(acc[i][0], acc[i][1], acc[i][2], acc[i][3]);
                    *(float4*)(p + 4) = make_float4(acc[i][4], acc[i][5], acc[i][6], acc[i][7]);
                } else {
                    float4 a = *(const float4*)p;
                    float4 b = *(const float4*)(p + 4);
                    a.x += acc[i][0]; a.y += acc[i][1]; a.z += acc[i][2]; a.w += acc[i][3];
                    b.x += acc[i][4]; b.y += acc[i][5]; b.z += acc[i][6]; b.w += acc[i][7];
                    *(float4*)p = a;
                    *(float4*)(p + 4) = b;
                }
            }
        }
        __syncthreads();
    }

    float* slot = part + ((size_t)chunk * NHEAD + head) * SLOT;
    #pragma unroll
    for (int q = 0; q < 4; ++q) {
        int f = q * 1024 + t * 4;          // coalesced across lanes
        *(float4*)&slot[f] = *(const float4*)&red[f];
    }
    if (t < Dn)
        slot[Dn * Dn + t] = ksr[t] + ksr[Dn + t] + ksr[2 * Dn + t] + ksr[3 * Dn + t];
}

// ---------------- Reduce chunk-partials -> final slot layout [head][4096 kv + 64 ksum] ----------------
__global__ __launch_bounds__(256) void reduce_partials(const float* __restrict__ part,
                                                       float* __restrict__ slots,
                                                       int nchunks) {
    const int head = blockIdx.x;
    const int idx = blockIdx.y * 256 + threadIdx.x;
    if (idx >= SLOT) return;
    float s = 0.f;
    for (int c = 0; c < nchunks; ++c)
        s += part[((size_t)c * NHEAD + head) * SLOT + idx];
    slots[(size_t)head * SLOT + idx] = s;
}

// ---------------- Pass 2: out = (Q / (Q.ksum + eps)) @ kv ----------------
__global__ __launch_bounds__(256) void pass2(const float* __restrict__ Q,
                                             const float* __restrict__ slots,
                                             float* __restrict__ out) {
    const int head = blockIdx.x;
    const int rc = blockIdx.y;  // 64-row chunk
    const int t = threadIdx.x;
    const int ti = t >> 4, tj = t & 15;
    const int r0 = ti * 4, e0 = tj * 4;   // 4 rows x 4 cols per thread

    __shared__ float kvs[Dn][Dn];
    __shared__ float qT[Dn][68];          // transposed Q tile, padded
    __shared__ float kss[Dn];

    const float* kvh = slots + (size_t)head * SLOT;

    // stage kv (16KB; L2/L3-resident after reduce)
    const float4* kvsrc = (const float4*)kvh;
    float4* kvdst = (float4*)&kvs[0][0];
    #pragma unroll
    for (int kk = 0; kk < 4; ++kk) kvdst[t + 256 * kk] = kvsrc[t + 256 * kk];
    if (t < 16) ((float4*)kss)[t] = ((const float4*)(kvh + Dn * Dn))[t];

    // stage Q tile transposed: qT[d][row]
    const float4* Qsrc = (const float4*)(Q + ((size_t)head * Sn + (size_t)rc * 64) * Dn);
    #pragma unroll
    for (int kk = 0; kk < 4; ++kk) {
        int f = t + 256 * kk;
        int row = f >> 4, d4 = (f & 15) * 4;
        float4 q4 = Qsrc[f];
        qT[d4 + 0][row] = q4.x;
        qT[d4 + 1][row] = q4.y;
        qT[d4 + 2][row] = q4.z;
        qT[d4 + 3][row] = q4.w;
    }
    __syncthreads();

    float acc[4][4] = {};
    float dn[4] = {0.f, 0.f, 0.f, 0.f};
    #pragma unroll 8
    for (int d = 0; d < Dn; ++d) {
        float4 a = *(const float4*)&qT[d][r0];     // q for 4 rows at dim d
        float4 b = *(const float4*)&kvs[d][e0];    // kv row d, 4 cols
        float ksd = kss[d];
        float av[4] = {a.x, a.y, a.z, a.w};
        float bv[4] = {b.x, b.y, b.z, b.w};
        #pragma unroll
        for (int i = 0; i < 4; ++i) {
            dn[i] += av[i] * ksd;
            #pragma unroll
            for (int j = 0; j < 4; ++j) acc[i][j] += av[i] * bv[j];
        }
    }

    float* Oh = out + ((size_t)head * Sn + (size_t)rc * 64) * Dn;
    #pragma unroll
    for (int i = 0; i < 4; ++i) {
        float inv = 1.0f / (dn[i] + FEPS);
        float4 r;
        r.x = acc[i][0] * inv; r.y = acc[i][1] * inv;
        r.z = acc[i][2] * inv; r.w = acc[i][3] * inv;
        *(float4*)&Oh[(size_t)(r0 + i) * Dn + e0] = r;
    }
}

extern "C" void kernel_launch(void* const* d_in, const int* in_sizes, int n_in,
                              void* d_out, int out_size, void* d_ws, size_t ws_size,
                              hipStream_t stream) {
    (void)in_sizes; (void)n_in; (void)out_size;
    const float* Q = (const float*)d_in[0];
    const float* K = (const float*)d_in[1];
    const float* V = (const float*)d_in[2];
    float* out = (float*)d_out;

    float* slots = (float*)d_ws;                         // [64][4160] final kv+ksum

    // pick the largest chunk count whose partial buffer fits in d_ws
    int chunks = 1;
    const int cand[5] = {32, 16, 8, 4, 2};
    for (int ci = 0; ci < 5; ++ci) {
        if ((size_t)(1 + cand[ci]) * NHEAD * SLOT * sizeof(float) <= ws_size) {
            chunks = cand[ci];
            break;
        }
    }

    if (chunks > 1) {
        float* part = slots + (size_t)NHEAD * SLOT;      // [chunks][64][4160]
        hipLaunchKernelGGL(pass1, dim3(NHEAD, chunks), dim3(256), 0, stream,
                           K, V, part, Sn / chunks);
        hipLaunchKernelGGL(reduce_partials, dim3(NHEAD, (SLOT + 255) / 256), dim3(256), 0, stream,
                           part, slots, chunks);
    } else {
        // one block per head writes the final slot directly (no reduce needed)
        hipLaunchKernelGGL(pass1, dim3(NHEAD, 1), dim3(256), 0, stream,
                           K, V, slots, Sn);
    }
    hipLaunchKernelGGL(pass2, dim3(NHEAD, Sn / 64), dim3(256), 0, stream,
                       Q, slots, out);
}

// Round 8
// 106.371 us; speedup vs baseline: 5.0531x; 5.0531x over previous
//
#include <hip/hip_runtime.h>

#define FEPS 1e-5f

constexpr int Bn = 4, Hn = 16, Sn = 4096, Dn = 64;
constexpr int NHEAD = Bn * Hn;          // 64 heads
constexpr int SLOT = Dn * Dn + Dn;      // 4160 floats: kv then ksum

// ---------------- Pass 1: partial kv = K^T V and k_sum over an S-chunk ----------------
// Register-staged, wave-private pipeline (R6 main loop, byte-for-byte):
//   per stage: global float4 -> regs (next stage) | compute current stage from
//   this wave's own LDS quarter | ds_write regs -> same quarter. No barriers
//   in the loop.
// R8 change: LDS shrunk 17KB -> 9KB. Evidence (R2/R6/R7): blocks/CU ==
// floor(64KB / LDS_block) -- the occupancy-relevant LDS pool is 64KB, so
// 33KB => 2 blocks/CU was the plateau. 9KB => ~6 blocks/CU (VGPR-capped).
// Epilogue reduces kv in TWO 64x32 e-halves through a 2048-float buffer.
// launch_bounds stays (256,3): (256,4)/(256,5) forced VGPR<=64 and spilled
// acc[8][8] (R4: 1.8GB, R7: 0.65GB scratch traffic).
__global__ __launch_bounds__(256, 3) void pass1(const float* __restrict__ K,
                                                const float* __restrict__ V,
                                                float* __restrict__ part,
                                                int ch_s) {
    // loop: [0..1023] K staging, [1024..2047] V staging
    // epilogue: [0..2047] red (64x32 half), [2048..2303] ksred
    __shared__ float lds[2304];   // 9216 B

    const int head = blockIdx.x;
    const int chunk = blockIdx.y;
    const int t = threadIdx.x;
    const int w = t >> 6;                  // wave 0..3
    const int l = t & 63;
    const int d0 = (l >> 3) * 8;           // kv row-tile base (K dim)
    const int e0 = (l & 7) * 8;            // kv col-tile base (V dim)
    const int nstg = ch_s / 16;            // 16 rows per stage block-wide, 4 per wave

    const size_t base = ((size_t)head * Sn + (size_t)chunk * ch_s) * Dn;
    // wave w owns rows [w*4, w*4+4) of every 16-row stage
    const float* Kg = K + base + (size_t)w * 256 + l * 4;   // + st*1024 per stage
    const float* Vg = V + base + (size_t)w * 256 + l * 4;

    float* kq = &lds[w * 256];             // this wave's K quarter (4 rows x 64)
    float* vq = &lds[1024 + w * 256];      // this wave's V quarter

    float acc[8][8] = {};
    float ks[8] = {};

    // prologue: stage 0 into LDS
    {
        float4 kr = *(const float4*)Kg;
        float4 vr = *(const float4*)Vg;
        *(float4*)(kq + l * 4) = kr;
        *(float4*)(vq + l * 4) = vr;
    }

    for (int st = 0; st < nstg; ++st) {
        float4 kn, vn;
        const bool more = (st + 1 < nstg);
        if (more) {
            kn = *(const float4*)(Kg + (size_t)(st + 1) * 1024);
            vn = *(const float4*)(Vg + (size_t)(st + 1) * 1024);
        }
        // compute this wave's 4 rows of the current stage
        #pragma unroll
        for (int r = 0; r < 4; ++r) {
            float4 ka = *(const float4*)(kq + r * 64 + d0);
            float4 kc = *(const float4*)(kq + r * 64 + d0 + 4);
            float4 va = *(const float4*)(vq + r * 64 + e0);
            float4 vc = *(const float4*)(vq + r * 64 + e0 + 4);
            float kf[8] = {ka.x, ka.y, ka.z, ka.w, kc.x, kc.y, kc.z, kc.w};
            float vf[8] = {va.x, va.y, va.z, va.w, vc.x, vc.y, vc.z, vc.w};
            #pragma unroll
            for (int i = 0; i < 8; ++i) {
                ks[i] += kf[i];
                #pragma unroll
                for (int j = 0; j < 8; ++j) acc[i][j] += kf[i] * vf[j];
            }
        }
        // overwrite the just-consumed quarter with the next stage (in-order DS)
        if (more) {
            *(float4*)(kq + l * 4) = kn;
            *(float4*)(vq + l * 4) = vn;
        }
    }

    // ---- epilogue: reduce 4 wave partials in two 64x32 e-halves ----
    __syncthreads();                       // all waves done with staging area
    float* red = &lds[0];                  // 2048 floats: red[d][eo] = red[d*32+eo]
    float* ksr = &lds[2048];               // 256 floats
    if ((l & 7) == 0) {                    // 8 lanes/wave hold ks for d0..d0+7
        #pragma unroll
        for (int i = 0; i < 8; ++i) ksr[w * Dn + d0 + i] = ks[i];
    }

    float* slot = part + ((size_t)chunk * NHEAD + head) * SLOT;
    const int myhalf = e0 >> 5;            // which e-half this lane's tile is in
    const int eo = e0 & 31;
    #pragma unroll
    for (int half = 0; half < 2; ++half) {
        #pragma unroll
        for (int ww = 0; ww < 4; ++ww) {
            if (w == ww && myhalf == half) {
                #pragma unroll
                for (int i = 0; i < 8; ++i) {
                    float* p = &red[(d0 + i) * 32 + eo];
                    if (ww == 0) {
                        *(float4*)p = make_float4(acc[i][0], acc[i][1], acc[i][2], acc[i][3]);
                        *(float4*)(p + 4) = make_float4(acc[i][4], acc[i][5], acc[i][6], acc[i][7]);
                    } else {
                        float4 a = *(const float4*)p;
                        float4 b = *(const float4*)(p + 4);
                        a.x += acc[i][0]; a.y += acc[i][1]; a.z += acc[i][2]; a.w += acc[i][3];
                        b.x += acc[i][4]; b.y += acc[i][5]; b.z += acc[i][6]; b.w += acc[i][7];
                        *(float4*)p = a;
                        *(float4*)(p + 4) = b;
                    }
                }
            }
            __syncthreads();
        }
        // write this half: red[d][eo] -> slot[d*64 + half*32 + eo]
        #pragma unroll
        for (int q = 0; q < 2; ++q) {
            int f = q * 1024 + t * 4;      // 0..2047
            int d = f >> 5, o = f & 31;
            *(float4*)&slot[d * Dn + half * 32 + o] = *(const float4*)&red[f];
        }
        __syncthreads();                   // half written; red reusable
    }
    if (t < Dn)
        slot[Dn * Dn + t] = ksr[t] + ksr[Dn + t] + ksr[2 * Dn + t] + ksr[3 * Dn + t];
}

// ---------------- Reduce chunk-partials -> final slot layout [head][4096 kv + 64 ksum] ----------------
__global__ __launch_bounds__(256) void reduce_partials(const float* __restrict__ part,
                                                       float* __restrict__ slots,
                                                       int nchunks) {
    const int head = blockIdx.x;
    const int idx = blockIdx.y * 256 + threadIdx.x;
    if (idx >= SLOT) return;
    float s = 0.f;
    for (int c = 0; c < nchunks; ++c)
        s += part[((size_t)c * NHEAD + head) * SLOT + idx];
    slots[(size_t)head * SLOT + idx] = s;
}

// ---------------- Pass 2: out = (Q / (Q.ksum + eps)) @ kv ----------------
__global__ __launch_bounds__(256) void pass2(const float* __restrict__ Q,
                                             const float* __restrict__ slots,
                                             float* __restrict__ out) {
    const int head = blockIdx.x;
    const int rc = blockIdx.y;  // 64-row chunk
    const int t = threadIdx.x;
    const int ti = t >> 4, tj = t & 15;
    const int r0 = ti * 4, e0 = tj * 4;   // 4 rows x 4 cols per thread

    __shared__ float kvs[Dn][Dn];
    __shared__ float qT[Dn][68];          // transposed Q tile, padded
    __shared__ float kss[Dn];

    const float* kvh = slots + (size_t)head * SLOT;

    // stage kv (16KB; L2/L3-resident after reduce)
    const float4* kvsrc = (const float4*)kvh;
    float4* kvdst = (float4*)&kvs[0][0];
    #pragma unroll
    for (int kk = 0; kk < 4; ++kk) kvdst[t + 256 * kk] = kvsrc[t + 256 * kk];
    if (t < 16) ((float4*)kss)[t] = ((const float4*)(kvh + Dn * Dn))[t];

    // stage Q tile transposed: qT[d][row]
    const float4* Qsrc = (const float4*)(Q + ((size_t)head * Sn + (size_t)rc * 64) * Dn);
    #pragma unroll
    for (int kk = 0; kk < 4; ++kk) {
        int f = t + 256 * kk;
        int row = f >> 4, d4 = (f & 15) * 4;
        float4 q4 = Qsrc[f];
        qT[d4 + 0][row] = q4.x;
        qT[d4 + 1][row] = q4.y;
        qT[d4 + 2][row] = q4.z;
        qT[d4 + 3][row] = q4.w;
    }
    __syncthreads();

    float acc[4][4] = {};
    float dn[4] = {0.f, 0.f, 0.f, 0.f};
    #pragma unroll 8
    for (int d = 0; d < Dn; ++d) {
        float4 a = *(const float4*)&qT[d][r0];     // q for 4 rows at dim d
        float4 b = *(const float4*)&kvs[d][e0];    // kv row d, 4 cols
        float ksd = kss[d];
        float av[4] = {a.x, a.y, a.z, a.w};
        float bv[4] = {b.x, b.y, b.z, b.w};
        #pragma unroll
        for (int i = 0; i < 4; ++i) {
            dn[i] += av[i] * ksd;
            #pragma unroll
            for (int j = 0; j < 4; ++j) acc[i][j] += av[i] * bv[j];
        }
    }

    float* Oh = out + ((size_t)head * Sn + (size_t)rc * 64) * Dn;
    #pragma unroll
    for (int i = 0; i < 4; ++i) {
        float inv = 1.0f / (dn[i] + FEPS);
        float4 r;
        r.x = acc[i][0] * inv; r.y = acc[i][1] * inv;
        r.z = acc[i][2] * inv; r.w = acc[i][3] * inv;
        *(float4*)&Oh[(size_t)(r0 + i) * Dn + e0] = r;
    }
}

extern "C" void kernel_launch(void* const* d_in, const int* in_sizes, int n_in,
                              void* d_out, int out_size, void* d_ws, size_t ws_size,
                              hipStream_t stream) {
    (void)in_sizes; (void)n_in; (void)out_size;
    const float* Q = (const float*)d_in[0];
    const float* K = (const float*)d_in[1];
    const float* V = (const float*)d_in[2];
    float* out = (float*)d_out;

    float* slots = (float*)d_ws;                         // [64][4160] final kv+ksum

    // pick the largest chunk count whose partial buffer fits in d_ws
    int chunks = 1;
    const int cand[5] = {32, 16, 8, 4, 2};
    for (int ci = 0; ci < 5; ++ci) {
        if ((size_t)(1 + cand[ci]) * NHEAD * SLOT * sizeof(float) <= ws_size) {
            chunks = cand[ci];
            break;
        }
    }

    if (chunks > 1) {
        float* part = slots + (size_t)NHEAD * SLOT;      // [chunks][64][4160]
        hipLaunchKernelGGL(pass1, dim3(NHEAD, chunks), dim3(256), 0, stream,
                           K, V, part, Sn / chunks);
        hipLaunchKernelGGL(reduce_partials, dim3(NHEAD, (SLOT + 255) / 256), dim3(256), 0, stream,
                           part, slots, chunks);
    } else {
        // one block per head writes the final slot directly (no reduce needed)
        hipLaunchKernelGGL(pass1, dim3(NHEAD, 1), dim3(256), 0, stream,
                           K, V, slots, Sn);
    }
    hipLaunchKernelGGL(pass2, dim3(NHEAD, Sn / 64), dim3(256), 0, stream,
                       Q, slots, out);
}

// Round 9
// 77.436 us; speedup vs baseline: 6.9413x; 1.3737x over previous
//
#include <hip/hip_runtime.h>
#include <hip/hip_bf16.h>

#define FEPS 1e-5f

constexpr int Bn = 4, Hn = 16, Sn = 4096, Dn = 64;
constexpr int NHEAD = Bn * Hn;          // 64 heads
constexpr int SLOT = Dn * Dn + Dn;      // 4160 floats: kv then ksum

typedef short short8 __attribute__((ext_vector_type(8)));
typedef float f32x4 __attribute__((ext_vector_type(4)));

__device__ __forceinline__ short f2bf(float f) {
    __hip_bfloat16 h = __float2bfloat16(f);
    return __builtin_bit_cast(short, h);
}

// ---------------- Pass 1 (MFMA): partial kv = K^T V and k_sum over an S-chunk ----------------
// Per (head, chunk) block: 4 waves, each wave owns ch_s/4 s-rows and computes a
// full 64x64 kv partial via mfma_f32_16x16x32_bf16 (4x4 tiles of 16x16,
// acc = 64 VGPR). NO LDS in the main loop: each lane gathers its A (K^T) and
// B (V) fragment slots directly from global — slot j of A and B use the SAME
// s-row ((l>>4)*8 + j), so the k-sum is correct under ANY operand k-layout
// (permutation invariance). ksum accumulated in fp32 from pre-cvt values.
// C/D layout (HW-verified m89): col = lane&15, row = (lane>>4)*4 + reg.
__global__ __launch_bounds__(256, 2) void pass1(const float* __restrict__ K,
                                                const float* __restrict__ V,
                                                float* __restrict__ part,
                                                int ch_s) {
    __shared__ float red[2048];   // 64 x 32 e-half reduction buffer
    __shared__ float ksr[256];    // per-wave ksum partials

    const int head = blockIdx.x;
    const int chunk = blockIdx.y;
    const int t = threadIdx.x;
    const int w = t >> 6;                  // wave 0..3
    const int l = t & 63;
    const int q16 = l >> 4;                // lane group 0..3
    const int lc = l & 15;                 // col within 16-tile
    const int wave_s = ch_s >> 2;          // s-rows per wave
    const int nsl = wave_s >> 5;           // 32-row slices per wave

    const size_t hbase = (size_t)head * Sn * Dn;
    const size_t s0w = (size_t)chunk * ch_s + (size_t)w * wave_s;
    // per-lane gather base: row = s0w + q16*8 (+j), col = lc (+mt*16)
    const float* Kp = K + hbase + (s0w + q16 * 8) * Dn + lc;
    const float* Vp = V + hbase + (s0w + q16 * 8) * Dn + lc;

    f32x4 acc[4][4] = {};                  // [mt(d-tile)][nt(e-tile)]
    float ks[4] = {0.f, 0.f, 0.f, 0.f};    // fp32 ksum partial, d = mt*16+lc

    for (int sl = 0; sl < nsl; ++sl) {
        const float* kp = Kp + (size_t)sl * 32 * Dn;
        const float* vp = Vp + (size_t)sl * 32 * Dn;
        short8 af[4], bf[4];
        #pragma unroll
        for (int mt = 0; mt < 4; ++mt) {
            float f[8];
            #pragma unroll
            for (int j = 0; j < 8; ++j) f[j] = kp[j * Dn + mt * 16];
            short8 a;
            #pragma unroll
            for (int j = 0; j < 8; ++j) { a[j] = f2bf(f[j]); ks[mt] += f[j]; }
            af[mt] = a;
        }
        #pragma unroll
        for (int nt = 0; nt < 4; ++nt) {
            float f[8];
            #pragma unroll
            for (int j = 0; j < 8; ++j) f[j] = vp[j * Dn + nt * 16];
            short8 b;
            #pragma unroll
            for (int j = 0; j < 8; ++j) b[j] = f2bf(f[j]);
            bf[nt] = b;
        }
        #pragma unroll
        for (int mt = 0; mt < 4; ++mt)
            #pragma unroll
            for (int nt = 0; nt < 4; ++nt)
                acc[mt][nt] = __builtin_amdgcn_mfma_f32_16x16x32_bf16(
                    af[mt], bf[nt], acc[mt][nt], 0, 0, 0);
    }

    // ksum: lane covers only its q16-group's s-rows -> reduce across groups
    #pragma unroll
    for (int mt = 0; mt < 4; ++mt) {
        ks[mt] += __shfl_xor(ks[mt], 16);
        ks[mt] += __shfl_xor(ks[mt], 32);
    }
    if (l < 16) {
        #pragma unroll
        for (int mt = 0; mt < 4; ++mt) ksr[w * Dn + mt * 16 + l] = ks[mt];
    }

    // ---- epilogue: reduce 4 wave partials in two 64x32 e-halves ----
    float* slot = part + ((size_t)chunk * NHEAD + head) * SLOT;
    #pragma unroll
    for (int h = 0; h < 2; ++h) {
        #pragma unroll
        for (int ww = 0; ww < 4; ++ww) {
            __syncthreads();
            if (w == ww) {
                #pragma unroll
                for (int mt = 0; mt < 4; ++mt)
                    #pragma unroll
                    for (int nh = 0; nh < 2; ++nh) {   // nt = h*2 + nh
                        #pragma unroll
                        for (int r = 0; r < 4; ++r) {
                            int row = mt * 16 + q16 * 4 + r;
                            int col = nh * 16 + lc;
                            float v = acc[mt][h * 2 + nh][r];
                            if (ww == 0) red[row * 32 + col] = v;
                            else         red[row * 32 + col] += v;
                        }
                    }
            }
        }
        __syncthreads();
        // write this e-half: red[d][eo] -> slot[d*64 + h*32 + eo]
        #pragma unroll
        for (int q = 0; q < 2; ++q) {
            int f = q * 1024 + t * 4;      // 0..2047
            int d = f >> 5, eo = f & 31;
            *(float4*)&slot[d * Dn + h * 32 + eo] = *(const float4*)&red[f];
        }
    }
    if (t < Dn)
        slot[Dn * Dn + t] = ksr[t] + ksr[Dn + t] + ksr[2 * Dn + t] + ksr[3 * Dn + t];
}

// ---------------- Reduce chunk-partials -> final slot layout [head][4096 kv + 64 ksum] ----------------
__global__ __launch_bounds__(256) void reduce_partials(const float* __restrict__ part,
                                                       float* __restrict__ slots,
                                                       int nchunks) {
    const int head = blockIdx.x;
    const int idx = blockIdx.y * 256 + threadIdx.x;
    if (idx >= SLOT) return;
    float s = 0.f;
    for (int c = 0; c < nchunks; ++c)
        s += part[((size_t)c * NHEAD + head) * SLOT + idx];
    slots[(size_t)head * SLOT + idx] = s;
}

// ---------------- Pass 2: out = (Q / (Q.ksum + eps)) @ kv ----------------
__global__ __launch_bounds__(256) void pass2(const float* __restrict__ Q,
                                             const float* __restrict__ slots,
                                             float* __restrict__ out) {
    const int head = blockIdx.x;
    const int rc = blockIdx.y;  // 64-row chunk
    const int t = threadIdx.x;
    const int ti = t >> 4, tj = t & 15;
    const int r0 = ti * 4, e0 = tj * 4;   // 4 rows x 4 cols per thread

    __shared__ float kvs[Dn][Dn];
    __shared__ float qT[Dn][68];          // transposed Q tile, padded
    __shared__ float kss[Dn];

    const float* kvh = slots + (size_t)head * SLOT;

    // stage kv (16KB; L2/L3-resident after reduce)
    const float4* kvsrc = (const float4*)kvh;
    float4* kvdst = (float4*)&kvs[0][0];
    #pragma unroll
    for (int kk = 0; kk < 4; ++kk) kvdst[t + 256 * kk] = kvsrc[t + 256 * kk];
    if (t < 16) ((float4*)kss)[t] = ((const float4*)(kvh + Dn * Dn))[t];

    // stage Q tile transposed: qT[d][row]
    const float4* Qsrc = (const float4*)(Q + ((size_t)head * Sn + (size_t)rc * 64) * Dn);
    #pragma unroll
    for (int kk = 0; kk < 4; ++kk) {
        int f = t + 256 * kk;
        int row = f >> 4, d4 = (f & 15) * 4;
        float4 q4 = Qsrc[f];
        qT[d4 + 0][row] = q4.x;
        qT[d4 + 1][row] = q4.y;
        qT[d4 + 2][row] = q4.z;
        qT[d4 + 3][row] = q4.w;
    }
    __syncthreads();

    float acc[4][4] = {};
    float dn[4] = {0.f, 0.f, 0.f, 0.f};
    #pragma unroll 8
    for (int d = 0; d < Dn; ++d) {
        float4 a = *(const float4*)&qT[d][r0];     // q for 4 rows at dim d
        float4 b = *(const float4*)&kvs[d][e0];    // kv row d, 4 cols
        float ksd = kss[d];
        float av[4] = {a.x, a.y, a.z, a.w};
        float bv[4] = {b.x, b.y, b.z, b.w};
        #pragma unroll
        for (int i = 0; i < 4; ++i) {
            dn[i] += av[i] * ksd;
            #pragma unroll
            for (int j = 0; j < 4; ++j) acc[i][j] += av[i] * bv[j];
        }
    }

    float* Oh = out + ((size_t)head * Sn + (size_t)rc * 64) * Dn;
    #pragma unroll
    for (int i = 0; i < 4; ++i) {
        float inv = 1.0f / (dn[i] + FEPS);
        float4 r;
        r.x = acc[i][0] * inv; r.y = acc[i][1] * inv;
        r.z = acc[i][2] * inv; r.w = acc[i][3] * inv;
        *(float4*)&Oh[(size_t)(r0 + i) * Dn + e0] = r;
    }
}

extern "C" void kernel_launch(void* const* d_in, const int* in_sizes, int n_in,
                              void* d_out, int out_size, void* d_ws, size_t ws_size,
                              hipStream_t stream) {
    (void)in_sizes; (void)n_in; (void)out_size;
    const float* Q = (const float*)d_in[0];
    const float* K = (const float*)d_in[1];
    const float* V = (const float*)d_in[2];
    float* out = (float*)d_out;

    float* slots = (float*)d_ws;                         // [64][4160] final kv+ksum

    // pick the largest chunk count whose partial buffer fits in d_ws
    int chunks = 1;
    const int cand[4] = {16, 8, 4, 2};
    for (int ci = 0; ci < 4; ++ci) {
        if ((size_t)(1 + cand[ci]) * NHEAD * SLOT * sizeof(float) <= ws_size) {
            chunks = cand[ci];
            break;
        }
    }

    if (chunks > 1) {
        float* part = slots + (size_t)NHEAD * SLOT;      // [chunks][64][4160]
        hipLaunchKernelGGL(pass1, dim3(NHEAD, chunks), dim3(256), 0, stream,
                           K, V, part, Sn / chunks);
        hipLaunchKernelGGL(reduce_partials, dim3(NHEAD, (SLOT + 255) / 256), dim3(256), 0, stream,
                           part, slots, chunks);
    } else {
        // one block per head writes the final slot directly (no reduce needed)
        hipLaunchKernelGGL(pass1, dim3(NHEAD, 1), dim3(256), 0, stream,
                           K, V, slots, Sn);
    }
    hipLaunchKernelGGL(pass2, dim3(NHEAD, Sn / 64), dim3(256), 0, stream,
                       Q, slots, out);
}